// Round 1
// baseline (60941.858 us; speedup 1.0000x reference)
//
#include <hip/hip_runtime.h>
#include <hip/hip_bf16.h>
#include <math.h>

typedef __bf16 bf16x8 __attribute__((ext_vector_type(8)));
typedef float f32x4 __attribute__((ext_vector_type(4)));

#define BB 64
#define TT 512
#define ISZ 1024
#define HSZ 4096
#define NBLK 256
#define NTHR 256
#define LN_EPS 1e-6f

// ---------------- prep kernels (run every call; ~50us total) ----------------
// w1p layout: [nblk 256][kgrp 256][col 16][kk 8] bf16  (64 KB per nblk, = LDS image)
__global__ void prep_w1(const float* __restrict__ W1, __bf16* __restrict__ w1p) {
  int t = blockIdx.x * blockDim.x + threadIdx.x;   // 1048576 threads
  int k = t >> 9;
  int n8 = (t & 511) << 3;
  const float* src = W1 + (size_t)k * HSZ + n8;
  float4 f0 = *(const float4*)src;
  float4 f1 = *(const float4*)(src + 4);
  int kgrp = k >> 3, kk = k & 7;
  float vals[8] = {f0.x, f0.y, f0.z, f0.w, f1.x, f1.y, f1.z, f1.w};
#pragma unroll
  for (int i = 0; i < 8; ++i) {
    int n = n8 + i;
    int nb = n >> 4, col = n & 15;
    w1p[(size_t)nb * 32768 + kgrp * 128 + col * 8 + kk] = (__bf16)vals[i];
  }
}

// w2p layout: [cg 64][kgrp 512][col 16][kk 8] bf16
__global__ void prep_w2(const float* __restrict__ W2, __bf16* __restrict__ w2p) {
  int t = blockIdx.x * blockDim.x + threadIdx.x;   // 524288 threads
  int k = t >> 7;
  int n8 = (t & 127) << 3;
  const float* src = W2 + (size_t)k * ISZ + n8;
  float4 f0 = *(const float4*)src;
  float4 f1 = *(const float4*)(src + 4);
  int kgrp = k >> 3, kk = k & 7;
  float vals[8] = {f0.x, f0.y, f0.z, f0.w, f1.x, f1.y, f1.z, f1.w};
#pragma unroll
  for (int i = 0; i < 8; ++i) {
    int n = n8 + i;
    int cg = n >> 4, col = n & 15;
    w2p[(size_t)cg * 65536 + kgrp * 128 + col * 8 + kk] = (__bf16)vals[i];
  }
}

// hxbf layout: [kh 32][m 4][lane 64][kk 8] bf16 — GEMM1 A-fragment image of hx
__global__ void prep_state(const float* __restrict__ init_hx,
                           float* __restrict__ hxf32, __bf16* __restrict__ hxbf,
                           float* __restrict__ stats, unsigned* __restrict__ bar) {
  int t = blockIdx.x * blockDim.x + threadIdx.x;   // 65536 threads
  int row = t >> 10, c = t & 1023;
  float v = init_hx[c];
  hxf32[t] = v;
  int kh = c >> 5, l = ((c >> 3) & 3) * 16 + (row & 15), m = row >> 4;
  hxbf[((kh * 4 + m) * 64 + l) * 8 + (c & 7)] = (__bf16)v;
  if (t < 256) stats[t] = 0.f;
  if (t == 0) *bar = 0u;
}

// ---------------- device-wide barrier (monotonic counter) ----------------
__device__ __forceinline__ void gbar(unsigned* bar, unsigned target) {
  __syncthreads();
  if (threadIdx.x == 0) {
    __threadfence();
    __hip_atomic_fetch_add(bar, 1u, __ATOMIC_RELEASE, __HIP_MEMORY_SCOPE_AGENT);
    int guard = 0;
    while (__hip_atomic_load(bar, __ATOMIC_ACQUIRE, __HIP_MEMORY_SCOPE_AGENT) < target) {
      __builtin_amdgcn_s_sleep(2);
      if (++guard > (1 << 24)) break;   // fail-safe: wrong answer beats a hang
    }
  }
  __syncthreads();
}

// ---------------- persistent RNN kernel ----------------
__global__ __launch_bounds__(NTHR, 1) void rnn_persist(
    const float* __restrict__ x, const float* __restrict__ b1,
    const float* __restrict__ ln_g, const float* __restrict__ ln_b,
    const float* __restrict__ b2, float* __restrict__ out,
    const __bf16* __restrict__ w1p, const __bf16* __restrict__ w2p,
    __bf16* __restrict__ hxbf, float* __restrict__ hxf32,
    __bf16* __restrict__ abf, float* __restrict__ stats,
    unsigned* __restrict__ bar)
{
  __shared__ __bf16 w1s[32768];   // 64 KB: [kgrp 256][col 16][kk 8]
  __shared__ float red[4096];     // 16 KB reduction buffer
  __shared__ __bf16 abuf[1024];   // 2 KB: [row 64][col 16]

  const int j = blockIdx.x;
  const int tid = threadIdx.x;
  const int w = tid >> 6;
  const int l = tid & 63;
  const int l4 = l >> 4, l15 = l & 15;

  { // stage this block's W1 slice into LDS (one-time)
    const bf16x8* src = (const bf16x8*)(w1p + (size_t)j * 32768);
    bf16x8* dst = (bf16x8*)w1s;
#pragma unroll
    for (int i = 0; i < 16; ++i) dst[tid + i * 256] = src[tid + i * 256];
  }

  const int n0 = j * 16;                 // S1 column base
  const float b1v = b1[n0 + l15];
  const float gv  = ln_g[n0 + l15];
  const float bv  = ln_b[n0 + l15];
  const int g = j >> 6, cg = j & 63;     // S2 tile: rows 16g.., cols 16cg..
  const float b2v = b2[cg * 16 + l15];

  unsigned target = 0;
  __syncthreads();

  for (int t = 0; t < TT; ++t) {
    // ---------- Phase A: h[:, n0:n0+16] = cat(x_t, hx) @ W1 + b1, + row stats ----------
    f32x4 hac[4];
#pragma unroll
    for (int m = 0; m < 4; ++m) hac[m] = (f32x4){0.f, 0.f, 0.f, 0.f};
    const int ks0 = w * 16;              // K split across waves
    for (int ks = ks0; ks < ks0 + 16; ++ks) {
      bf16x8 bfr = *(const bf16x8*)&w1s[((4 * ks + l4) * 16 + l15) * 8];
      if (ks < 32) {                     // x half of cat
        const int k = ks * 32 + l4 * 8;
#pragma unroll
        for (int m = 0; m < 4; ++m) {
          const int row = m * 16 + l15;
          const float* p = x + ((size_t)row * TT + t) * ISZ + k;
          float4 f0 = *(const float4*)p;
          float4 f1 = *(const float4*)(p + 4);
          bf16x8 af;
          af[0] = (__bf16)f0.x; af[1] = (__bf16)f0.y;
          af[2] = (__bf16)f0.z; af[3] = (__bf16)f0.w;
          af[4] = (__bf16)f1.x; af[5] = (__bf16)f1.y;
          af[6] = (__bf16)f1.z; af[7] = (__bf16)f1.w;
          hac[m] = __builtin_amdgcn_mfma_f32_16x16x32_bf16(af, bfr, hac[m], 0, 0, 0);
        }
      } else {                           // hx half of cat (bf16 fragment image)
        const int kh = ks - 32;
#pragma unroll
        for (int m = 0; m < 4; ++m) {
          bf16x8 af = *(const bf16x8*)&hxbf[((kh * 4 + m) * 64 + l) * 8];
          hac[m] = __builtin_amdgcn_mfma_f32_16x16x32_bf16(af, bfr, hac[m], 0, 0, 0);
        }
      }
    }
    // cross-wave K reduction; wave w keeps m-tile w
#pragma unroll
    for (int m = 0; m < 4; ++m)
      *(f32x4*)&red[((w * 4 + m) * 64 + l) * 4] = hac[m];
    __syncthreads();
    f32x4 h = *(f32x4*)&red[((0 * 4 + w) * 64 + l) * 4];
#pragma unroll
    for (int s = 1; s < 4; ++s)
      h += *(f32x4*)&red[((s * 4 + w) * 64 + l) * 4];
#pragma unroll
    for (int r = 0; r < 4; ++r) h[r] += b1v;

    float* st = stats + (t & 1) * 128;   // [64][2] double-buffered
#pragma unroll
    for (int r = 0; r < 4; ++r) {        // C layout: col=l15, row=16w+4*l4+r
      float sv = h[r], qv = h[r] * h[r];
#pragma unroll
      for (int msk = 1; msk < 16; msk <<= 1) {
        sv += __shfl_xor(sv, msk, 64);
        qv += __shfl_xor(qv, msk, 64);
      }
      if (l15 == 0) {
        const int row = w * 16 + l4 * 4 + r;
        atomicAdd(&st[row * 2 + 0], sv);
        atomicAdd(&st[row * 2 + 1], qv);
      }
    }
    target += NBLK; gbar(bar, target);

    // ---------- Phase B: LN + exact GELU + repack into abf (GEMM2 A-frag image) ----------
#pragma unroll
    for (int r = 0; r < 4; ++r) {
      const int row = w * 16 + l4 * 4 + r;
      const float mu   = st[row * 2 + 0] * (1.f / 4096.f);
      const float var  = st[row * 2 + 1] * (1.f / 4096.f) - mu * mu;
      const float rstd = rsqrtf(var + LN_EPS);
      const float v  = (h[r] - mu) * rstd * gv + bv;
      const float ge = 0.5f * v * (1.f + erff(v * 0.70710678118654752f));
      abuf[row * 16 + l15] = (__bf16)ge;
    }
    __syncthreads();
    if (tid < 128) {                     // coalesced b128 stores of the block's a-slice
      const int m = tid >> 5, q2s = (tid >> 4) & 1, rr = tid & 15;
      const int row = m * 16 + rr;
      bf16x8 vv = *(const bf16x8*)&abuf[row * 16 + q2s * 8];
      const int k2 = j >> 1;
      const int q2 = (j & 1) * 2 + q2s;
      *(bf16x8*)&abf[(((k2 * 4 + m) * 64) + q2 * 16 + rr) * 8] = vv;
    }
    target += NBLK; gbar(bar, target);

    // ---------- Phase C: hx_new[16g.., 16cg..] = a @ W2 + b2 + hx ----------
    {
      f32x4 cac = {0.f, 0.f, 0.f, 0.f};
      for (int s2 = w * 32; s2 < w * 32 + 32; ++s2) {   // K split across waves
        bf16x8 af  = *(const bf16x8*)&abf[((s2 * 4 + g) * 64 + l) * 8];
        bf16x8 bfr = *(const bf16x8*)&w2p[((size_t)cg * 512 + s2 * 4 + l4) * 128 + l15 * 8];
        cac = __builtin_amdgcn_mfma_f32_16x16x32_bf16(af, bfr, cac, 0, 0, 0);
      }
      *(f32x4*)&red[(w * 64 + l) * 4] = cac;
    }
    __syncthreads();
    if (w == 0) {
      f32x4 s = *(f32x4*)&red[(0 * 64 + l) * 4];
#pragma unroll
      for (int src = 1; src < 4; ++src)
        s += *(f32x4*)&red[(src * 64 + l) * 4];
#pragma unroll
      for (int r = 0; r < 4; ++r) {
        const int row = g * 16 + l4 * 4 + r;
        const int c = cg * 16 + l15;
        const float vOld = hxf32[row * ISZ + c];
        const float vNew = s[r] + b2v + vOld;
        hxf32[row * ISZ + c] = vNew;
        out[((size_t)row * TT + t) * ISZ + c] = vNew;
        const int kh = c >> 5, lh = ((c >> 3) & 3) * 16 + (row & 15), mh = row >> 4;
        hxbf[((kh * 4 + mh) * 64 + lh) * 8 + (c & 7)] = (__bf16)vNew;
      }
    }
    if (j == 0 && tid < 128) stats[((t + 1) & 1) * 128 + tid] = 0.f;  // zero other parity
    target += NBLK; gbar(bar, target);
  }
}

// ---------------- host ----------------
extern "C" void kernel_launch(void* const* d_in, const int* in_sizes, int n_in,
                              void* d_out, int out_size, void* d_ws, size_t ws_size,
                              hipStream_t stream) {
  const float* x       = (const float*)d_in[0];
  const float* W1      = (const float*)d_in[1];
  const float* b1      = (const float*)d_in[2];
  const float* ln_g    = (const float*)d_in[3];
  const float* ln_b    = (const float*)d_in[4];
  const float* W2      = (const float*)d_in[5];
  const float* b2      = (const float*)d_in[6];
  const float* init_hx = (const float*)d_in[7];
  float* out = (float*)d_out;

  char* ws = (char*)d_ws;
  __bf16* w1p   = (__bf16*)(ws);                                   // 16 MB
  __bf16* w2p   = (__bf16*)(ws + (size_t)(16u << 20));             // 8 MB
  __bf16* abf   = (__bf16*)(ws + (size_t)(24u << 20));             // 512 KB
  __bf16* hxbf  = (__bf16*)(ws + (size_t)(24u << 20) + (512u << 10)); // 128 KB
  float* hxf32  = (float*)(ws + (size_t)(24u << 20) + (640u << 10));  // 256 KB
  float* stats  = (float*)(ws + (size_t)(24u << 20) + (896u << 10));  // 1 KB
  unsigned* bar = (unsigned*)(ws + (size_t)(24u << 20) + (897u << 10));

  prep_w1<<<4096, 256, 0, stream>>>(W1, w1p);
  prep_w2<<<2048, 256, 0, stream>>>(W2, w2p);
  prep_state<<<256, 256, 0, stream>>>(init_hx, hxf32, hxbf, stats, bar);
  rnn_persist<<<NBLK, NTHR, 0, stream>>>(
      x, b1, ln_g, ln_b, b2, out, w1p, w2p, hxbf, hxf32, abf, stats, bar);
}

// Round 2
// 31214.304 us; speedup vs baseline: 1.9524x; 1.9524x over previous
//
#include <hip/hip_runtime.h>
#include <hip/hip_bf16.h>
#include <math.h>

typedef __bf16 bf16x8 __attribute__((ext_vector_type(8)));
typedef float f32x4 __attribute__((ext_vector_type(4)));

#define TT 512
#define ISZ 1024
#define HSZ 4096
#define NBLK 256
#define NTHR 512
#define LN_EPS 1e-6f
#define SCOPE_AGENT __HIP_MEMORY_SCOPE_AGENT

// ---------------- prep kernels ----------------
// w1p layout: [nblk 256][kgrp 256][col 16][kk 8] bf16  (64 KB per nblk = LDS image)
__global__ void prep_w1(const float* __restrict__ W1, __bf16* __restrict__ w1p) {
  int t = blockIdx.x * blockDim.x + threadIdx.x;   // 1048576 threads
  int k = t >> 9;
  int n8 = (t & 511) << 3;
  const float* src = W1 + (size_t)k * HSZ + n8;
  float4 f0 = *(const float4*)src;
  float4 f1 = *(const float4*)(src + 4);
  int kgrp = k >> 3, kk = k & 7;
  float vals[8] = {f0.x, f0.y, f0.z, f0.w, f1.x, f1.y, f1.z, f1.w};
#pragma unroll
  for (int i = 0; i < 8; ++i) {
    int n = n8 + i;
    int nb = n >> 4, col = n & 15;
    w1p[(size_t)nb * 32768 + kgrp * 128 + col * 8 + kk] = (__bf16)vals[i];
  }
}

// w2p layout: [cg 64][kgrp 512][col 16][kk 8] bf16
__global__ void prep_w2(const float* __restrict__ W2, __bf16* __restrict__ w2p) {
  int t = blockIdx.x * blockDim.x + threadIdx.x;   // 524288 threads
  int k = t >> 7;
  int n8 = (t & 127) << 3;
  const float* src = W2 + (size_t)k * ISZ + n8;
  float4 f0 = *(const float4*)src;
  float4 f1 = *(const float4*)(src + 4);
  int kgrp = k >> 3, kk = k & 7;
  float vals[8] = {f0.x, f0.y, f0.z, f0.w, f1.x, f1.y, f1.z, f1.w};
#pragma unroll
  for (int i = 0; i < 8; ++i) {
    int n = n8 + i;
    int cg = n >> 4, col = n & 15;
    w2p[(size_t)cg * 65536 + kgrp * 128 + col * 8 + kk] = (__bf16)vals[i];
  }
}

// xbf layout per t: [kh 32][m 4][lane 64][kk 8] bf16 (128 KB) — GEMM1 A-frag image
__global__ void prep_x(const float* __restrict__ x, __bf16* __restrict__ xbf) {
  int tid = blockIdx.x * blockDim.x + threadIdx.x;  // 4194304 threads
  int c8 = tid & 127;
  int t = (tid >> 7) & 511;
  int row = tid >> 16;
  const float* src = x + ((size_t)row * TT + t) * ISZ + c8 * 8;
  float4 f0 = *(const float4*)src;
  float4 f1 = *(const float4*)(src + 4);
  float vals[8] = {f0.x, f0.y, f0.z, f0.w, f1.x, f1.y, f1.z, f1.w};
  bf16x8 v;
#pragma unroll
  for (int i = 0; i < 8; ++i) v[i] = (__bf16)vals[i];
  int kh = c8 >> 2, lane = (c8 & 3) * 16 + (row & 15), m = row >> 4;
  *(bf16x8*)&xbf[(size_t)t * 65536 + (((kh * 4 + m) * 64 + lane) << 3)] = v;
}

// hxbf layout: [kh 32][m 4][lane 64][kk 8] bf16
__global__ void prep_state(const float* __restrict__ init_hx,
                           float* __restrict__ hxf32, __bf16* __restrict__ hxbf,
                           float* __restrict__ stats, unsigned* __restrict__ cnt) {
  int t = blockIdx.x * blockDim.x + threadIdx.x;   // 65536 threads
  int row = t >> 10, c = t & 1023;
  float v = init_hx[c];
  hxf32[t] = v;
  int kh = c >> 5, l = ((c >> 3) & 3) * 16 + (row & 15), m = row >> 4;
  hxbf[((kh * 4 + m) * 64 + l) * 8 + (c & 7)] = (__bf16)v;
  if (t < 2048) stats[t] = 0.f;
  if (t < 16) cnt[t] = 0u;
}

// ------------- hierarchical device barrier: 8 group counters + root -------------
__device__ __forceinline__ void gbar(unsigned* cnt, int grp, unsigned rootTarget) {
  __syncthreads();
  if (threadIdx.x == 0) {
    unsigned old = __hip_atomic_fetch_add(&cnt[grp], 1u, __ATOMIC_RELEASE, SCOPE_AGENT);
    if ((old & 31u) == 31u)
      __hip_atomic_fetch_add(&cnt[8], 1u, __ATOMIC_RELEASE, SCOPE_AGENT);
    int guard = 0;
    while (__hip_atomic_load(&cnt[8], __ATOMIC_RELAXED, SCOPE_AGENT) < rootTarget) {
      __builtin_amdgcn_s_sleep(2);
      if (++guard > (1 << 16)) break;   // fail-safe: wrong answer beats a hang
    }
    (void)__hip_atomic_load(&cnt[8], __ATOMIC_ACQUIRE, SCOPE_AGENT);
  }
  __syncthreads();
}

// ---------------- persistent RNN kernel ----------------
template <bool USE_XBF>
__global__ __launch_bounds__(NTHR, 1) void rnn_persist(
    const float* __restrict__ x, const float* __restrict__ b1,
    const float* __restrict__ ln_g, const float* __restrict__ ln_b,
    const float* __restrict__ b2, float* __restrict__ out,
    const __bf16* __restrict__ w1p, const __bf16* __restrict__ w2p,
    const __bf16* __restrict__ xbf,
    __bf16* __restrict__ hbf, __bf16* __restrict__ hxbf,
    float* __restrict__ hxf32, float* __restrict__ stats,
    unsigned* __restrict__ cnt)
{
  __shared__ __bf16 w1s[32768];   // 64 KB [kgrp 256][col 16][kk 8]
  __shared__ float red[8192];     // 32 KB cross-wave reduction
  __shared__ __bf16 abuf[1024];   // 2 KB h-tile repack

  const int j = blockIdx.x;
  const int tid = threadIdx.x;
  const int w = tid >> 6;
  const int l = tid & 63;
  const int l4 = l >> 4, l15 = l & 15;
  const int grp = j & 7;

  { // stage this block's W1 slice into LDS (one-time)
    const bf16x8* src = (const bf16x8*)(w1p + (size_t)j * 32768);
    bf16x8* dst = (bf16x8*)w1s;
#pragma unroll
    for (int i = 0; i < 8; ++i) dst[tid + i * 512] = src[tid + i * 512];
  }

  const int n0 = j * 16;                 // phase-A column base
  const float b1v = b1[n0 + l15];
  const int g = j >> 6, cg = j & 63;     // phase-C tile: rows 16g.., cols 16cg..
  const float b2v = b2[cg * 16 + l15];

  unsigned rootTarget = 0;
  __syncthreads();

  for (int t = 0; t < TT; ++t) {
    // ---------- Phase A: h[:, n0:n0+16] = cat(x_t, hx) @ W1 + b1; write pre-LN bf16 h ----------
    f32x4 hac[4];
#pragma unroll
    for (int m = 0; m < 4; ++m) hac[m] = (f32x4){0.f, 0.f, 0.f, 0.f};
    const int ks0 = w * 8;               // K split across 8 waves
    if (w < 4) {                         // x half (ks 0..31)
      for (int ks = ks0; ks < ks0 + 8; ++ks) {
        bf16x8 bfr = *(const bf16x8*)&w1s[((4 * ks + l4) * 16 + l15) * 8];
        if (USE_XBF) {
          const __bf16* xb = xbf + (size_t)t * 65536 + (size_t)ks * 2048;
#pragma unroll
          for (int m = 0; m < 4; ++m) {
            bf16x8 af = *(const bf16x8*)&xb[(m * 64 + l) * 8];
            hac[m] = __builtin_amdgcn_mfma_f32_16x16x32_bf16(af, bfr, hac[m], 0, 0, 0);
          }
        } else {
          const int k = ks * 32 + l4 * 8;
#pragma unroll
          for (int m = 0; m < 4; ++m) {
            const int row = m * 16 + l15;
            const float* p = x + ((size_t)row * TT + t) * ISZ + k;
            float4 f0 = *(const float4*)p;
            float4 f1 = *(const float4*)(p + 4);
            bf16x8 af;
            af[0] = (__bf16)f0.x; af[1] = (__bf16)f0.y;
            af[2] = (__bf16)f0.z; af[3] = (__bf16)f0.w;
            af[4] = (__bf16)f1.x; af[5] = (__bf16)f1.y;
            af[6] = (__bf16)f1.z; af[7] = (__bf16)f1.w;
            hac[m] = __builtin_amdgcn_mfma_f32_16x16x32_bf16(af, bfr, hac[m], 0, 0, 0);
          }
        }
      }
    } else {                             // hx half (ks 32..63)
      for (int ks = ks0; ks < ks0 + 8; ++ks) {
        bf16x8 bfr = *(const bf16x8*)&w1s[((4 * ks + l4) * 16 + l15) * 8];
        const int kh = ks - 32;
#pragma unroll
        for (int m = 0; m < 4; ++m) {
          bf16x8 af = *(const bf16x8*)&hxbf[((kh * 4 + m) * 64 + l) * 8];
          hac[m] = __builtin_amdgcn_mfma_f32_16x16x32_bf16(af, bfr, hac[m], 0, 0, 0);
        }
      }
    }
#pragma unroll
    for (int m = 0; m < 4; ++m)
      *(f32x4*)&red[((w * 4 + m) * 64 + l) * 4] = hac[m];
    __syncthreads();
    if (w < 4) {                         // wave w owns m-tile w: rows 16w..16w+16
      f32x4 h = *(const f32x4*)&red[((0 * 4 + w) * 64 + l) * 4];
#pragma unroll
      for (int s = 1; s < 8; ++s)
        h += *(const f32x4*)&red[((s * 4 + w) * 64 + l) * 4];
#pragma unroll
      for (int r = 0; r < 4; ++r) h[r] += b1v;
      float* st = stats + (t & 1) * 1024 + grp * 128;  // [parity][group 8][row 64][2]
#pragma unroll
      for (int r = 0; r < 4; ++r) {      // C layout: col=l15, row=16w+4*l4+r
        abuf[(w * 16 + l4 * 4 + r) * 16 + l15] = (__bf16)h[r];
        float sv = h[r], qv = h[r] * h[r];
#pragma unroll
        for (int msk = 1; msk < 16; msk <<= 1) {
          sv += __shfl_xor(sv, msk, 64);
          qv += __shfl_xor(qv, msk, 64);
        }
        if (l15 == 0) {
          const int row = w * 16 + l4 * 4 + r;
          __hip_atomic_fetch_add(&st[row * 2 + 0], sv, __ATOMIC_RELAXED, SCOPE_AGENT);
          __hip_atomic_fetch_add(&st[row * 2 + 1], qv, __ATOMIC_RELAXED, SCOPE_AGENT);
        }
      }
    }
    __syncthreads();
    if (tid < 128) {                     // vectorized copy of h-tile into hbf frag image
      const int m = tid >> 5, q2s = (tid >> 4) & 1, rr = tid & 15;
      bf16x8 vv = *(const bf16x8*)&abuf[(m * 16 + rr) * 16 + q2s * 8];
      const int k2 = j >> 1, q2 = (j & 1) * 2 + q2s;
      *(bf16x8*)&hbf[(((k2 * 4 + m) * 64) + q2 * 16 + rr) * 8] = vv;
    }
    rootTarget += 8; gbar(cnt, grp, rootTarget);

    // ---------- Phase C: hx_new[16g.., 16cg..] = gelu(LN(h)) @ W2 + b2 + hx ----------
    {
      const float* sp = stats + (t & 1) * 1024;
      float ssum = 0.f, ssq = 0.f;
      const int row16 = g * 16 + l15;    // A-frag row for this lane
#pragma unroll
      for (int q = 0; q < 8; ++q) {
        ssum += sp[(q * 64 + row16) * 2 + 0];
        ssq  += sp[(q * 64 + row16) * 2 + 1];
      }
      const float mu   = ssum * (1.f / 4096.f);
      const float var  = ssq * (1.f / 4096.f) - mu * mu;
      const float rstd = rsqrtf(var + LN_EPS);

      f32x4 cac = {0.f, 0.f, 0.f, 0.f};
      for (int s2 = w * 16; s2 < w * 16 + 16; ++s2) {  // K split across 8 waves
        bf16x8 hf = *(const bf16x8*)&hbf[((s2 * 4 + g) * 64 + l) * 8];
        const int k = s2 * 32 + l4 * 8;
        float4 g0 = *(const float4*)(ln_g + k);
        float4 g1 = *(const float4*)(ln_g + k + 4);
        float4 e0 = *(const float4*)(ln_b + k);
        float4 e1 = *(const float4*)(ln_b + k + 4);
        float gk[8] = {g0.x, g0.y, g0.z, g0.w, g1.x, g1.y, g1.z, g1.w};
        float ek[8] = {e0.x, e0.y, e0.z, e0.w, e1.x, e1.y, e1.z, e1.w};
        bf16x8 af;
#pragma unroll
        for (int i = 0; i < 8; ++i) {
          float v = ((float)hf[i] - mu) * rstd * gk[i] + ek[i];
          af[i] = (__bf16)(0.5f * v * (1.f + erff(v * 0.70710678118654752f)));
        }
        bf16x8 bfr = *(const bf16x8*)&w2p[((size_t)cg * 512 + s2 * 4 + l4) * 128 + l15 * 8];
        cac = __builtin_amdgcn_mfma_f32_16x16x32_bf16(af, bfr, cac, 0, 0, 0);
      }
      *(f32x4*)&red[(w * 64 + l) * 4] = cac;
    }
    __syncthreads();
    if (w == 0) {
      f32x4 s = *(const f32x4*)&red[(0 * 64 + l) * 4];
#pragma unroll
      for (int w2 = 1; w2 < 8; ++w2)
        s += *(const f32x4*)&red[(w2 * 64 + l) * 4];
#pragma unroll
      for (int r = 0; r < 4; ++r) {
        const int row = g * 16 + l4 * 4 + r;
        const int c = cg * 16 + l15;
        const float vNew = s[r] + b2v + hxf32[row * ISZ + c];
        hxf32[row * ISZ + c] = vNew;
        out[((size_t)row * TT + t) * ISZ + c] = vNew;
        const int kh = c >> 5, lh = ((c >> 3) & 3) * 16 + (row & 15), mh = row >> 4;
        hxbf[((kh * 4 + mh) * 64 + lh) * 8 + (c & 7)] = (__bf16)vNew;
      }
    }
    if (j == 0 && tid < 256) {           // zero next parity's stats
      float4 z = {0.f, 0.f, 0.f, 0.f};
      *(float4*)&stats[((t + 1) & 1) * 1024 + tid * 4] = z;
    }
    rootTarget += 8; gbar(cnt, grp, rootTarget);
  }
}

// ---------------- host ----------------
extern "C" void kernel_launch(void* const* d_in, const int* in_sizes, int n_in,
                              void* d_out, int out_size, void* d_ws, size_t ws_size,
                              hipStream_t stream) {
  const float* x       = (const float*)d_in[0];
  const float* W1      = (const float*)d_in[1];
  const float* b1      = (const float*)d_in[2];
  const float* ln_g    = (const float*)d_in[3];
  const float* ln_b    = (const float*)d_in[4];
  const float* W2      = (const float*)d_in[5];
  const float* b2      = (const float*)d_in[6];
  const float* init_hx = (const float*)d_in[7];
  float* out = (float*)d_out;

  char* ws = (char*)d_ws;
  __bf16* w1p   = (__bf16*)(ws);                        // 16 MB @ 0
  __bf16* w2p   = (__bf16*)(ws + 16777216ull);          // 8 MB
  __bf16* hbf   = (__bf16*)(ws + 25165824ull);          // 512 KB
  __bf16* hxbf  = (__bf16*)(ws + 25690112ull);          // 128 KB
  float* hxf32  = (float*)(ws + 25821184ull);           // 256 KB
  float* stats  = (float*)(ws + 26083328ull);           // 8 KB
  unsigned* cnt = (unsigned*)(ws + 26091520ull);        // 64 B
  __bf16* xbf   = (__bf16*)(ws + 28311552ull);          // 64 MB @ 27 MB
  const bool use_xbf = (ws_size >= 28311552ull + 67108864ull);

  prep_w1<<<4096, 256, 0, stream>>>(W1, w1p);
  prep_w2<<<2048, 256, 0, stream>>>(W2, w2p);
  prep_state<<<256, 256, 0, stream>>>(init_hx, hxf32, hxbf, stats, cnt);
  if (use_xbf) {
    prep_x<<<16384, 256, 0, stream>>>(x, xbf);
    rnn_persist<true><<<NBLK, NTHR, 0, stream>>>(
        x, b1, ln_g, ln_b, b2, out, w1p, w2p, xbf, hbf, hxbf, hxf32, stats, cnt);
  } else {
    rnn_persist<false><<<NBLK, NTHR, 0, stream>>>(
        x, b1, ln_g, ln_b, b2, out, w1p, w2p, xbf, hbf, hxbf, hxf32, stats, cnt);
  }
}

// Round 3
// 24573.328 us; speedup vs baseline: 2.4800x; 1.2703x over previous
//
#include <hip/hip_runtime.h>
#include <hip/hip_bf16.h>
#include <math.h>

typedef __bf16 bf16x8 __attribute__((ext_vector_type(8)));
typedef float f32x4 __attribute__((ext_vector_type(4)));

#define TT 512
#define ISZ 1024
#define HSZ 4096
#define NBLK 256
#define NTHR 512
#define LN_EPS 1e-6f
#define SCOPE_AGENT __HIP_MEMORY_SCOPE_AGENT

// ---------------- prep kernels ----------------
// w1p layout: [nblk 256][kgrp 256][col 16][kk 8] bf16  (64 KB per nblk = LDS image)
__global__ void prep_w1(const float* __restrict__ W1, __bf16* __restrict__ w1p) {
  int t = blockIdx.x * blockDim.x + threadIdx.x;   // 1048576 threads
  int k = t >> 9;
  int n8 = (t & 511) << 3;
  const float* src = W1 + (size_t)k * HSZ + n8;
  float4 f0 = *(const float4*)src;
  float4 f1 = *(const float4*)(src + 4);
  int kgrp = k >> 3, kk = k & 7;
  float vals[8] = {f0.x, f0.y, f0.z, f0.w, f1.x, f1.y, f1.z, f1.w};
#pragma unroll
  for (int i = 0; i < 8; ++i) {
    int n = n8 + i;
    int nb = n >> 4, col = n & 15;
    w1p[(size_t)nb * 32768 + kgrp * 128 + col * 8 + kk] = (__bf16)vals[i];
  }
}

// w2p layout: [cg 64][kgrp 512][col 16][kk 8] bf16
__global__ void prep_w2(const float* __restrict__ W2, __bf16* __restrict__ w2p) {
  int t = blockIdx.x * blockDim.x + threadIdx.x;   // 524288 threads
  int k = t >> 7;
  int n8 = (t & 127) << 3;
  const float* src = W2 + (size_t)k * ISZ + n8;
  float4 f0 = *(const float4*)src;
  float4 f1 = *(const float4*)(src + 4);
  int kgrp = k >> 3, kk = k & 7;
  float vals[8] = {f0.x, f0.y, f0.z, f0.w, f1.x, f1.y, f1.z, f1.w};
#pragma unroll
  for (int i = 0; i < 8; ++i) {
    int n = n8 + i;
    int cg = n >> 4, col = n & 15;
    w2p[(size_t)cg * 65536 + kgrp * 128 + col * 8 + kk] = (__bf16)vals[i];
  }
}

// xbf layout per t: [kh 32][m 4][lane 64][kk 8] bf16 (128 KB) — GEMM1 A-frag image
__global__ void prep_x(const float* __restrict__ x, __bf16* __restrict__ xbf) {
  int tid = blockIdx.x * blockDim.x + threadIdx.x;  // 4194304 threads
  int c8 = tid & 127;
  int t = (tid >> 7) & 511;
  int row = tid >> 16;
  const float* src = x + ((size_t)row * TT + t) * ISZ + c8 * 8;
  float4 f0 = *(const float4*)src;
  float4 f1 = *(const float4*)(src + 4);
  float vals[8] = {f0.x, f0.y, f0.z, f0.w, f1.x, f1.y, f1.z, f1.w};
  bf16x8 v;
#pragma unroll
  for (int i = 0; i < 8; ++i) v[i] = (__bf16)vals[i];
  int kh = c8 >> 2, lane = (c8 & 3) * 16 + (row & 15), m = row >> 4;
  *(bf16x8*)&xbf[(size_t)t * 65536 + (((kh * 4 + m) * 64 + lane) << 3)] = v;
}

// hxbf layout: [kh 32][m 4][lane 64][kk 8] bf16
__global__ void prep_state(const float* __restrict__ init_hx,
                           float* __restrict__ hxf32, __bf16* __restrict__ hxbf,
                           unsigned* __restrict__ syncbuf) {
  int t = blockIdx.x * blockDim.x + threadIdx.x;   // 65536 threads
  int row = t >> 10, c = t & 1023;
  float v = init_hx[c];
  hxf32[t] = v;
  int kh = c >> 5, l = ((c >> 3) & 3) * 16 + (row & 15), m = row >> 4;
  hxbf[((kh * 4 + m) * 64 + l) * 8 + (c & 7)] = (__bf16)v;
  if (t < 16384) syncbuf[t] = 0u;       // arrival flags + group flags
}

// ------- flag-based hierarchical barrier: no RMW chains, 3 coherence hops -------
// arr: 256 flags, one per 128B line.  gflag: 8 flags, one per 128B line.
__device__ __forceinline__ void gbar(unsigned* __restrict__ arr,
                                     unsigned* __restrict__ gflag,
                                     int j, unsigned target) {
  __syncthreads();
  const int tid = threadIdx.x;
  if (tid == 0) {                        // arrival: plain release-store, own line
    __builtin_amdgcn_fence(__ATOMIC_RELEASE, "agent");
    __hip_atomic_store(&arr[j * 32], target, __ATOMIC_RELAXED, SCOPE_AGENT);
  }
  if (j < 8 && tid < 32) {               // aggregator for group j: poll 32 lines
    const unsigned* p = &arr[(tid * 8 + j) * 32];
    int guard = 0;
    for (;;) {
      unsigned v = __hip_atomic_load(p, __ATOMIC_RELAXED, SCOPE_AGENT);
      if (__all(v >= target)) break;
      if (++guard > (1 << 18)) break;    // fail-safe: wrong answer beats a hang
      __builtin_amdgcn_s_sleep(4);
    }
    if (tid == 0) {
      __builtin_amdgcn_fence(__ATOMIC_ACQUIRE, "agent");
      __builtin_amdgcn_fence(__ATOMIC_RELEASE, "agent");
      __hip_atomic_store(&gflag[j * 32], target, __ATOMIC_RELAXED, SCOPE_AGENT);
    }
  }
  if (tid < 8) {                         // everyone: poll the 8 group flags
    const unsigned* p = &gflag[tid * 32];
    int guard = 0;
    for (;;) {
      unsigned v = __hip_atomic_load(p, __ATOMIC_RELAXED, SCOPE_AGENT);
      if (__all(v >= target)) break;
      if (++guard > (1 << 18)) break;
      __builtin_amdgcn_s_sleep(4);
    }
  }
  if (tid == 0) __builtin_amdgcn_fence(__ATOMIC_ACQUIRE, "agent");
  __syncthreads();
}

// ---------------- persistent RNN kernel ----------------
template <bool USE_XBF>
__global__ __launch_bounds__(NTHR, 1) void rnn_persist(
    const float* __restrict__ x, const float* __restrict__ b1,
    const float* __restrict__ ln_g, const float* __restrict__ ln_b,
    const float* __restrict__ b2, float* __restrict__ out,
    const __bf16* __restrict__ w1p, const __bf16* __restrict__ w2p,
    const __bf16* __restrict__ xbf,
    __bf16* __restrict__ hbf, __bf16* __restrict__ hxbf,
    float* __restrict__ hxf32, unsigned* __restrict__ arr,
    unsigned* __restrict__ gflag)
{
  __shared__ __bf16 w1s[32768];   // 64 KB [kgrp 256][col 16][kk 8]
  __shared__ float red[8192];     // 32 KB: [0..2048) cac, [4096..4352) LN partials, A-phase full
  __shared__ __bf16 abuf[1024];   // 2 KB h-tile repack

  const int j = blockIdx.x;
  const int tid = threadIdx.x;
  const int w = tid >> 6;
  const int l = tid & 63;
  const int l4 = l >> 4, l15 = l & 15;

  { // stage this block's W1 slice into LDS (one-time)
    const bf16x8* src = (const bf16x8*)(w1p + (size_t)j * 32768);
    bf16x8* dst = (bf16x8*)w1s;
#pragma unroll
    for (int i = 0; i < 8; ++i) dst[tid + i * 512] = src[tid + i * 512];
  }

  const int n0 = j * 16;                 // phase-A column base
  const float b1v = b1[n0 + l15];
  const int g = j >> 6, cg = j & 63;     // phase-C tile: rows 16g.., cols 16cg..
  const float b2v = b2[cg * 16 + l15];

  unsigned target = 0;
  __syncthreads();

  for (int t = 0; t < TT; ++t) {
    // ---------- Phase A: h[:, n0:n0+16] = cat(x_t, hx) @ W1 + b1; write bf16 h ----------
    f32x4 hac[4];
#pragma unroll
    for (int m = 0; m < 4; ++m) hac[m] = (f32x4){0.f, 0.f, 0.f, 0.f};
    const int ks0 = w * 8;               // K split across 8 waves
    if (w < 4) {                         // x half (ks 0..31)
      for (int ks = ks0; ks < ks0 + 8; ++ks) {
        bf16x8 bfr = *(const bf16x8*)&w1s[((4 * ks + l4) * 16 + l15) * 8];
        if (USE_XBF) {
          const __bf16* xb = xbf + (size_t)t * 65536 + (size_t)ks * 2048;
#pragma unroll
          for (int m = 0; m < 4; ++m) {
            bf16x8 af = *(const bf16x8*)&xb[(m * 64 + l) * 8];
            hac[m] = __builtin_amdgcn_mfma_f32_16x16x32_bf16(af, bfr, hac[m], 0, 0, 0);
          }
        } else {
          const int k = ks * 32 + l4 * 8;
#pragma unroll
          for (int m = 0; m < 4; ++m) {
            const int row = m * 16 + l15;
            const float* p = x + ((size_t)row * TT + t) * ISZ + k;
            float4 f0 = *(const float4*)p;
            float4 f1 = *(const float4*)(p + 4);
            bf16x8 af;
            af[0] = (__bf16)f0.x; af[1] = (__bf16)f0.y;
            af[2] = (__bf16)f0.z; af[3] = (__bf16)f0.w;
            af[4] = (__bf16)f1.x; af[5] = (__bf16)f1.y;
            af[6] = (__bf16)f1.z; af[7] = (__bf16)f1.w;
            hac[m] = __builtin_amdgcn_mfma_f32_16x16x32_bf16(af, bfr, hac[m], 0, 0, 0);
          }
        }
      }
    } else {                             // hx half (ks 32..63)
      for (int ks = ks0; ks < ks0 + 8; ++ks) {
        bf16x8 bfr = *(const bf16x8*)&w1s[((4 * ks + l4) * 16 + l15) * 8];
        const int kh = ks - 32;
#pragma unroll
        for (int m = 0; m < 4; ++m) {
          bf16x8 af = *(const bf16x8*)&hxbf[((kh * 4 + m) * 64 + l) * 8];
          hac[m] = __builtin_amdgcn_mfma_f32_16x16x32_bf16(af, bfr, hac[m], 0, 0, 0);
        }
      }
    }
#pragma unroll
    for (int m = 0; m < 4; ++m)
      *(f32x4*)&red[((w * 4 + m) * 64 + l) * 4] = hac[m];
    __syncthreads();
    if (w < 4) {                         // wave w owns m-tile w: rows 16w..16w+16
      f32x4 h = *(const f32x4*)&red[((0 * 4 + w) * 64 + l) * 4];
#pragma unroll
      for (int s = 1; s < 8; ++s)
        h += *(const f32x4*)&red[((s * 4 + w) * 64 + l) * 4];
#pragma unroll
      for (int r = 0; r < 4; ++r)        // C layout: col=l15, row=16w+4*l4+r
        abuf[(w * 16 + l4 * 4 + r) * 16 + l15] = (__bf16)(h[r] + b1v);
    }
    __syncthreads();
    if (tid < 128) {                     // vectorized copy of h-tile into hbf frag image
      const int m = tid >> 5, q2s = (tid >> 4) & 1, rr = tid & 15;
      bf16x8 vv = *(const bf16x8*)&abuf[(m * 16 + rr) * 16 + q2s * 8];
      const int k2 = j >> 1, q2 = (j & 1) * 2 + q2s;
      *(bf16x8*)&hbf[(((k2 * 4 + m) * 64) + q2 * 16 + rr) * 8] = vv;
    }
    ++target; gbar(arr, gflag, j, target);

    // ---------- Phase C: hx_new[16g.., 16cg..] = gelu(LN(h)) @ W2 + b2 + hx ----------
    {
      // load this lane's 128 h values (row l15 of block rows, its 128 cols)
      bf16x8 hf[16];
#pragma unroll
      for (int i = 0; i < 16; ++i) {
        const int s2 = w * 16 + i;
        hf[i] = *(const bf16x8*)&hbf[((s2 * 4 + g) * 64 + l) * 8];
      }
      // local LN stats: per-lane partial, then 32-lane shfl, then 8-wave LDS reduce
      float ssum = 0.f, ssq = 0.f;
#pragma unroll
      for (int i = 0; i < 16; ++i)
#pragma unroll
        for (int e = 0; e < 8; ++e) {
          float v = (float)hf[i][e];
          ssum += v; ssq += v * v;
        }
      ssum += __shfl_xor(ssum, 16, 64); ssq += __shfl_xor(ssq, 16, 64);
      ssum += __shfl_xor(ssum, 32, 64); ssq += __shfl_xor(ssq, 32, 64);
      if (l < 16) {
        red[4096 + (w * 16 + l) * 2 + 0] = ssum;
        red[4096 + (w * 16 + l) * 2 + 1] = ssq;
      }
      __syncthreads();
      float S = 0.f, Q = 0.f;
#pragma unroll
      for (int q = 0; q < 8; ++q) {
        S += red[4096 + (q * 16 + l15) * 2 + 0];
        Q += red[4096 + (q * 16 + l15) * 2 + 1];
      }
      const float mu   = S * (1.f / 4096.f);
      const float var  = Q * (1.f / 4096.f) - mu * mu;
      const float rstd = rsqrtf(var + LN_EPS);

      f32x4 cac = {0.f, 0.f, 0.f, 0.f};
#pragma unroll 4
      for (int i = 0; i < 16; ++i) {
        const int s2 = w * 16 + i;
        const int k = s2 * 32 + l4 * 8;
        float4 g0 = *(const float4*)(ln_g + k);
        float4 g1 = *(const float4*)(ln_g + k + 4);
        float4 e0 = *(const float4*)(ln_b + k);
        float4 e1 = *(const float4*)(ln_b + k + 4);
        float gk[8] = {g0.x, g0.y, g0.z, g0.w, g1.x, g1.y, g1.z, g1.w};
        float ek[8] = {e0.x, e0.y, e0.z, e0.w, e1.x, e1.y, e1.z, e1.w};
        bf16x8 af;
#pragma unroll
        for (int e = 0; e < 8; ++e) {
          float v = ((float)hf[i][e] - mu) * rstd * gk[e] + ek[e];
          af[e] = (__bf16)(0.5f * v * (1.f + erff(v * 0.70710678118654752f)));
        }
        bf16x8 bfr = *(const bf16x8*)&w2p[((size_t)cg * 512 + s2 * 4 + l4) * 128 + l15 * 8];
        cac = __builtin_amdgcn_mfma_f32_16x16x32_bf16(af, bfr, cac, 0, 0, 0);
      }
      *(f32x4*)&red[(w * 64 + l) * 4] = cac;
    }
    __syncthreads();
    if (w == 0) {
      f32x4 s = *(const f32x4*)&red[(0 * 64 + l) * 4];
#pragma unroll
      for (int w2 = 1; w2 < 8; ++w2)
        s += *(const f32x4*)&red[(w2 * 64 + l) * 4];
#pragma unroll
      for (int r = 0; r < 4; ++r) {
        const int row = g * 16 + l4 * 4 + r;
        const int c = cg * 16 + l15;
        const float vNew = s[r] + b2v + hxf32[row * ISZ + c];
        hxf32[row * ISZ + c] = vNew;
        out[((size_t)row * TT + t) * ISZ + c] = vNew;
        const int kh = c >> 5, lh = ((c >> 3) & 3) * 16 + (row & 15), mh = row >> 4;
        hxbf[((kh * 4 + mh) * 64 + lh) * 8 + (c & 7)] = (__bf16)vNew;
      }
    }
    ++target; gbar(arr, gflag, j, target);
  }
}

// ---------------- host ----------------
extern "C" void kernel_launch(void* const* d_in, const int* in_sizes, int n_in,
                              void* d_out, int out_size, void* d_ws, size_t ws_size,
                              hipStream_t stream) {
  const float* x       = (const float*)d_in[0];
  const float* W1      = (const float*)d_in[1];
  const float* b1      = (const float*)d_in[2];
  const float* ln_g    = (const float*)d_in[3];
  const float* ln_b    = (const float*)d_in[4];
  const float* W2      = (const float*)d_in[5];
  const float* b2      = (const float*)d_in[6];
  const float* init_hx = (const float*)d_in[7];
  float* out = (float*)d_out;

  char* ws = (char*)d_ws;
  __bf16* w1p    = (__bf16*)(ws);                        // 16 MB @ 0
  __bf16* w2p    = (__bf16*)(ws + 16777216ull);          // 8 MB
  __bf16* hbf    = (__bf16*)(ws + 25165824ull);          // 512 KB
  __bf16* hxbf   = (__bf16*)(ws + 25690112ull);          // 128 KB
  float* hxf32   = (float*)(ws + 25821184ull);           // 256 KB
  unsigned* arr  = (unsigned*)(ws + 26083328ull);        // 32 KB arrival flags
  unsigned* gflag= (unsigned*)(ws + 26116096ull);        // 1 KB group flags
  __bf16* xbf    = (__bf16*)(ws + 28311552ull);          // 64 MB @ 27 MB
  const bool use_xbf = (ws_size >= 28311552ull + 67108864ull);

  prep_w1<<<4096, 256, 0, stream>>>(W1, w1p);
  prep_w2<<<2048, 256, 0, stream>>>(W2, w2p);
  prep_state<<<256, 256, 0, stream>>>(init_hx, hxf32, hxbf, arr);
  if (use_xbf) {
    prep_x<<<16384, 256, 0, stream>>>(x, xbf);
    rnn_persist<true><<<NBLK, NTHR, 0, stream>>>(
        x, b1, ln_g, ln_b, b2, out, w1p, w2p, xbf, hbf, hxbf, hxf32, arr, gflag);
  } else {
    rnn_persist<false><<<NBLK, NTHR, 0, stream>>>(
        x, b1, ln_g, ln_b, b2, out, w1p, w2p, xbf, hbf, hxbf, hxf32, arr, gflag);
  }
}

// Round 4
// 20528.966 us; speedup vs baseline: 2.9686x; 1.1970x over previous
//
#include <hip/hip_runtime.h>
#include <hip/hip_bf16.h>
#include <math.h>

typedef __bf16 bf16x8 __attribute__((ext_vector_type(8)));
typedef float f32x4 __attribute__((ext_vector_type(4)));
typedef unsigned long long u64;

#define TT 512
#define ISZ 1024
#define HSZ 4096
#define NBLK 256
#define NTHR 512
#define LN_EPS 1e-6f
#define SCOPE_AGENT __HIP_MEMORY_SCOPE_AGENT

union U128 { u64 u[2]; bf16x8 v; };

__device__ __forceinline__ bf16x8 coh_ld16(const __bf16* p) {
  U128 r;
  const u64* q = (const u64*)p;
  r.u[0] = __hip_atomic_load(q,     __ATOMIC_RELAXED, SCOPE_AGENT);
  r.u[1] = __hip_atomic_load(q + 1, __ATOMIC_RELAXED, SCOPE_AGENT);
  return r.v;
}
__device__ __forceinline__ void coh_st16(__bf16* p, bf16x8 v) {
  U128 r; r.v = v;
  u64* q = (u64*)p;
  __hip_atomic_store(q,     r.u[0], __ATOMIC_RELAXED, SCOPE_AGENT);
  __hip_atomic_store(q + 1, r.u[1], __ATOMIC_RELAXED, SCOPE_AGENT);
}

// exact-grade GELU: Abramowitz-Stegun 7.1.26 erf (|eps|<=1.5e-7), branchless
__device__ __forceinline__ float gelu_f(float v) {
  const float u = v * 0.70710678118654752f;
  const float x = fabsf(u);
  const float t = __builtin_amdgcn_rcpf(fmaf(0.3275911f, x, 1.0f));
  float p = fmaf(1.061405429f, t, -1.453152027f);
  p = fmaf(p, t, 1.421413741f);
  p = fmaf(p, t, -0.284496736f);
  p = fmaf(p, t, 0.254829592f);
  p = p * t;
  const float e = p * __expf(-x * x);
  const float erfv = copysignf(1.0f - e, u);
  return 0.5f * v * (1.0f + erfv);
}

// ---------------- prep kernels ----------------
// w1p layout: [nblk 256][kgrp 256][col 16][kk 8] bf16  (64 KB per nblk = LDS image)
__global__ void prep_w1(const float* __restrict__ W1, __bf16* __restrict__ w1p) {
  int t = blockIdx.x * blockDim.x + threadIdx.x;   // 1048576 threads
  int k = t >> 9;
  int n8 = (t & 511) << 3;
  const float* src = W1 + (size_t)k * HSZ + n8;
  float4 f0 = *(const float4*)src;
  float4 f1 = *(const float4*)(src + 4);
  int kgrp = k >> 3, kk = k & 7;
  float vals[8] = {f0.x, f0.y, f0.z, f0.w, f1.x, f1.y, f1.z, f1.w};
#pragma unroll
  for (int i = 0; i < 8; ++i) {
    int n = n8 + i;
    int nb = n >> 4, col = n & 15;
    w1p[(size_t)nb * 32768 + kgrp * 128 + col * 8 + kk] = (__bf16)vals[i];
  }
}

// w2p layout: [cg 64][kgrp 512][col 16][kk 8] bf16
__global__ void prep_w2(const float* __restrict__ W2, __bf16* __restrict__ w2p) {
  int t = blockIdx.x * blockDim.x + threadIdx.x;   // 524288 threads
  int k = t >> 7;
  int n8 = (t & 127) << 3;
  const float* src = W2 + (size_t)k * ISZ + n8;
  float4 f0 = *(const float4*)src;
  float4 f1 = *(const float4*)(src + 4);
  int kgrp = k >> 3, kk = k & 7;
  float vals[8] = {f0.x, f0.y, f0.z, f0.w, f1.x, f1.y, f1.z, f1.w};
#pragma unroll
  for (int i = 0; i < 8; ++i) {
    int n = n8 + i;
    int cg = n >> 4, col = n & 15;
    w2p[(size_t)cg * 65536 + kgrp * 128 + col * 8 + kk] = (__bf16)vals[i];
  }
}

// xbf layout per t: [kh 32][m 4][lane 64][kk 8] bf16 (128 KB) — GEMM1 A-frag image
__global__ void prep_x(const float* __restrict__ x, __bf16* __restrict__ xbf) {
  int tid = blockIdx.x * blockDim.x + threadIdx.x;  // 4194304 threads
  int c8 = tid & 127;
  int t = (tid >> 7) & 511;
  int row = tid >> 16;
  const float* src = x + ((size_t)row * TT + t) * ISZ + c8 * 8;
  float4 f0 = *(const float4*)src;
  float4 f1 = *(const float4*)(src + 4);
  float vals[8] = {f0.x, f0.y, f0.z, f0.w, f1.x, f1.y, f1.z, f1.w};
  bf16x8 v;
#pragma unroll
  for (int i = 0; i < 8; ++i) v[i] = (__bf16)vals[i];
  int kh = c8 >> 2, lane = (c8 & 3) * 16 + (row & 15), m = row >> 4;
  *(bf16x8*)&xbf[(size_t)t * 65536 + (((kh * 4 + m) * 64 + lane) << 3)] = v;
}

// hxbf layout: [kh 32][m 4][lane 64][kk 8] bf16
__global__ void prep_state(const float* __restrict__ init_hx,
                           float* __restrict__ hxf32, __bf16* __restrict__ hxbf,
                           unsigned* __restrict__ syncbuf) {
  int t = blockIdx.x * blockDim.x + threadIdx.x;   // 65536 threads
  int row = t >> 10, c = t & 1023;
  float v = init_hx[c];
  hxf32[t] = v;
  int kh = c >> 5, l = ((c >> 3) & 3) * 16 + (row & 15), m = row >> 4;
  hxbf[((kh * 4 + m) * 64 + l) * 8 + (c & 7)] = (__bf16)v;
  if (t < 16384) syncbuf[t] = 0u;       // arrival + group + epoch flags (64 KB)
}

// ---- fence-free 3-hop barrier: arrivals -> 8 aggregators -> super -> epoch ----
// All relaxed agent atomics; data ordering comes from the vmcnt drain that
// __syncthreads() performs (all shared-data stores are write-through agent ops).
__device__ __forceinline__ void gbar(unsigned* __restrict__ arr,
                                     unsigned* __restrict__ gflag,
                                     unsigned* __restrict__ epoch,
                                     int j, unsigned target) {
  __syncthreads();                       // drains vmcnt of every wave's stores
  const int tid = threadIdx.x;
  if (tid == 0)                          // arrival: own 128B line, no RMW
    __hip_atomic_store(&arr[j * 32], target, __ATOMIC_RELAXED, SCOPE_AGENT);
  if (j < 8 && tid < 32) {               // wave 0 of blocks 0..7: group aggregator
    const unsigned* p = &arr[(tid * 8 + j) * 32];
    int guard = 0;
    for (;;) {
      unsigned v = __hip_atomic_load(p, __ATOMIC_RELAXED, SCOPE_AGENT);
      if (__all(v >= target)) break;
      if (++guard > (1 << 20)) break;    // fail-safe: wrong answer beats a hang
      __builtin_amdgcn_s_sleep(2);
    }
    asm volatile("" ::: "memory");
    if (tid == 0)
      __hip_atomic_store(&gflag[j * 32], target, __ATOMIC_RELAXED, SCOPE_AGENT);
  }
  if (j == 0 && tid >= 64 && tid < 72) { // wave 1 of block 0: super-aggregator
    const unsigned* p = &gflag[(tid - 64) * 32];
    int guard = 0;
    for (;;) {
      unsigned v = __hip_atomic_load(p, __ATOMIC_RELAXED, SCOPE_AGENT);
      if (__all(v >= target)) break;
      if (++guard > (1 << 20)) break;
      __builtin_amdgcn_s_sleep(2);
    }
    asm volatile("" ::: "memory");
    if (tid == 64)
      __hip_atomic_store(epoch, target, __ATOMIC_RELAXED, SCOPE_AGENT);
  }
  if (tid == 128) {                      // wave 2, lane 0: poll the single epoch line
    int guard = 0;
    while (__hip_atomic_load(epoch, __ATOMIC_RELAXED, SCOPE_AGENT) < target) {
      if (++guard > (1 << 20)) break;
      __builtin_amdgcn_s_sleep(2);
    }
  }
  asm volatile("" ::: "memory");
  __syncthreads();
}

// ---------------- persistent RNN kernel ----------------
template <bool USE_XBF>
__global__ __launch_bounds__(NTHR, 1) void rnn_persist(
    const float* __restrict__ x, const float* __restrict__ b1,
    const float* __restrict__ ln_g, const float* __restrict__ ln_b,
    const float* __restrict__ b2, float* __restrict__ out,
    const __bf16* __restrict__ w1p, const __bf16* __restrict__ w2p,
    const __bf16* __restrict__ xbf,
    __bf16* __restrict__ hbf, __bf16* __restrict__ hxbf,
    float* __restrict__ hxf32, unsigned* __restrict__ arr,
    unsigned* __restrict__ gflag, unsigned* __restrict__ epoch)
{
  __shared__ __bf16 w1s[32768];   // 64 KB [kgrp 256][col 16][kk 8]
  __shared__ float red[8192];     // 32 KB cross-wave reduction + LN partials
  __shared__ __bf16 abuf[1024];   // 2 KB h-tile repack

  const int j = blockIdx.x;
  const int tid = threadIdx.x;
  const int w = tid >> 6;
  const int l = tid & 63;
  const int l4 = l >> 4, l15 = l & 15;

  { // stage this block's W1 slice into LDS (one-time)
    const bf16x8* src = (const bf16x8*)(w1p + (size_t)j * 32768);
    bf16x8* dst = (bf16x8*)w1s;
#pragma unroll
    for (int i = 0; i < 8; ++i) dst[tid + i * 512] = src[tid + i * 512];
  }

  const int n0 = j * 16;                 // phase-A column base
  const float b1v = b1[n0 + l15];
  const int g = j >> 6, cg = j & 63;     // phase-C tile: rows 16g.., cols 16cg..
  const float b2v = b2[cg * 16 + l15];

  unsigned target = 0;
  __syncthreads();

  for (int t = 0; t < TT; ++t) {
    // ---------- Phase A: h[:, n0:n0+16] = cat(x_t, hx) @ W1 + b1; write bf16 h ----------
    f32x4 hac[4];
#pragma unroll
    for (int m = 0; m < 4; ++m) hac[m] = (f32x4){0.f, 0.f, 0.f, 0.f};
    const int ks0 = w * 8;               // K split across 8 waves
    if (w < 4) {                         // x half (ks 0..31) — read-only, cached
      for (int ks = ks0; ks < ks0 + 8; ++ks) {
        bf16x8 bfr = *(const bf16x8*)&w1s[((4 * ks + l4) * 16 + l15) * 8];
        if (USE_XBF) {
          const __bf16* xb = xbf + (size_t)t * 65536 + (size_t)ks * 2048;
#pragma unroll
          for (int m = 0; m < 4; ++m) {
            bf16x8 af = *(const bf16x8*)&xb[(m * 64 + l) * 8];
            hac[m] = __builtin_amdgcn_mfma_f32_16x16x32_bf16(af, bfr, hac[m], 0, 0, 0);
          }
        } else {
          const int k = ks * 32 + l4 * 8;
#pragma unroll
          for (int m = 0; m < 4; ++m) {
            const int row = m * 16 + l15;
            const float* p = x + ((size_t)row * TT + t) * ISZ + k;
            float4 f0 = *(const float4*)p;
            float4 f1 = *(const float4*)(p + 4);
            bf16x8 af;
            af[0] = (__bf16)f0.x; af[1] = (__bf16)f0.y;
            af[2] = (__bf16)f0.z; af[3] = (__bf16)f0.w;
            af[4] = (__bf16)f1.x; af[5] = (__bf16)f1.y;
            af[6] = (__bf16)f1.z; af[7] = (__bf16)f1.w;
            hac[m] = __builtin_amdgcn_mfma_f32_16x16x32_bf16(af, bfr, hac[m], 0, 0, 0);
          }
        }
      }
    } else {                             // hx half (ks 32..63) — coherent fragment reads
      for (int ks = ks0; ks < ks0 + 8; ++ks) {
        bf16x8 bfr = *(const bf16x8*)&w1s[((4 * ks + l4) * 16 + l15) * 8];
        const int kh = ks - 32;
#pragma unroll
        for (int m = 0; m < 4; ++m) {
          bf16x8 af = coh_ld16(&hxbf[((kh * 4 + m) * 64 + l) * 8]);
          hac[m] = __builtin_amdgcn_mfma_f32_16x16x32_bf16(af, bfr, hac[m], 0, 0, 0);
        }
      }
    }
#pragma unroll
    for (int m = 0; m < 4; ++m)
      *(f32x4*)&red[((w * 4 + m) * 64 + l) * 4] = hac[m];
    __syncthreads();
    if (w < 4) {                         // wave w owns m-tile w: rows 16w..16w+16
      f32x4 h = *(const f32x4*)&red[((0 * 4 + w) * 64 + l) * 4];
#pragma unroll
      for (int s = 1; s < 8; ++s)
        h += *(const f32x4*)&red[((s * 4 + w) * 64 + l) * 4];
#pragma unroll
      for (int r = 0; r < 4; ++r)        // C layout: col=l15, row=16w+4*l4+r
        abuf[(w * 16 + l4 * 4 + r) * 16 + l15] = (__bf16)(h[r] + b1v);
    }
    __syncthreads();
    if (tid < 128) {                     // h-tile -> hbf frag image (coherent stores)
      const int m = tid >> 5, q2s = (tid >> 4) & 1, rr = tid & 15;
      bf16x8 vv = *(const bf16x8*)&abuf[(m * 16 + rr) * 16 + q2s * 8];
      const int k2 = j >> 1, q2 = (j & 1) * 2 + q2s;
      coh_st16(&hbf[(((k2 * 4 + m) * 64) + q2 * 16 + rr) * 8], vv);
    }
    ++target; gbar(arr, gflag, epoch, j, target);

    // ---------- Phase C: hx_new[16g.., 16cg..] = gelu(LN(h)) @ W2 + b2 + hx ----------
    {
      // coherent load of this lane's 128 h values
      bf16x8 hf[16];
#pragma unroll
      for (int i = 0; i < 16; ++i) {
        const int s2 = w * 16 + i;
        hf[i] = coh_ld16(&hbf[((s2 * 4 + g) * 64 + l) * 8]);
      }
      // local LN stats: per-lane partial, 32-lane shfl, 8-wave LDS reduce
      float ssum = 0.f, ssq = 0.f;
#pragma unroll
      for (int i = 0; i < 16; ++i)
#pragma unroll
        for (int e = 0; e < 8; ++e) {
          float v = (float)hf[i][e];
          ssum += v; ssq += v * v;
        }
      ssum += __shfl_xor(ssum, 16, 64); ssq += __shfl_xor(ssq, 16, 64);
      ssum += __shfl_xor(ssum, 32, 64); ssq += __shfl_xor(ssq, 32, 64);
      if (l < 16) {
        red[4096 + (w * 16 + l) * 2 + 0] = ssum;
        red[4096 + (w * 16 + l) * 2 + 1] = ssq;
      }
      __syncthreads();
      float S = 0.f, Q = 0.f;
#pragma unroll
      for (int q = 0; q < 8; ++q) {
        S += red[4096 + (q * 16 + l15) * 2 + 0];
        Q += red[4096 + (q * 16 + l15) * 2 + 1];
      }
      const float mu   = S * (1.f / 4096.f);
      const float var  = Q * (1.f / 4096.f) - mu * mu;
      const float rstd = rsqrtf(var + LN_EPS);

      f32x4 cac = {0.f, 0.f, 0.f, 0.f};
#pragma unroll 4
      for (int i = 0; i < 16; ++i) {
        const int s2 = w * 16 + i;
        const int k = s2 * 32 + l4 * 8;
        float4 g0 = *(const float4*)(ln_g + k);
        float4 g1 = *(const float4*)(ln_g + k + 4);
        float4 e0 = *(const float4*)(ln_b + k);
        float4 e1 = *(const float4*)(ln_b + k + 4);
        float gk[8] = {g0.x, g0.y, g0.z, g0.w, g1.x, g1.y, g1.z, g1.w};
        float ek[8] = {e0.x, e0.y, e0.z, e0.w, e1.x, e1.y, e1.z, e1.w};
        bf16x8 af;
#pragma unroll
        for (int e = 0; e < 8; ++e) {
          float v = ((float)hf[i][e] - mu) * rstd * gk[e] + ek[e];
          af[e] = (__bf16)gelu_f(v);
        }
        bf16x8 bfr = *(const bf16x8*)&w2p[((size_t)cg * 512 + s2 * 4 + l4) * 128 + l15 * 8];
        cac = __builtin_amdgcn_mfma_f32_16x16x32_bf16(af, bfr, cac, 0, 0, 0);
      }
      *(f32x4*)&red[(w * 64 + l) * 4] = cac;
    }
    __syncthreads();
    if (w == 0) {
      f32x4 s = *(const f32x4*)&red[(0 * 64 + l) * 4];
#pragma unroll
      for (int w2 = 1; w2 < 8; ++w2)
        s += *(const f32x4*)&red[(w2 * 64 + l) * 4];
#pragma unroll
      for (int r = 0; r < 4; ++r) {
        const int row = g * 16 + l4 * 4 + r;
        const int c = cg * 16 + l15;
        const float vNew = s[r] + b2v + hxf32[row * ISZ + c];   // private, cached
        hxf32[row * ISZ + c] = vNew;
        out[((size_t)row * TT + t) * ISZ + c] = vNew;           // write-once, cached
        const int kh = c >> 5, lh = ((c >> 3) & 3) * 16 + (row & 15), mh = row >> 4;
        union { __bf16 b; unsigned short s16; } cv; cv.b = (__bf16)vNew;
        __hip_atomic_store((unsigned short*)&hxbf[((kh * 4 + mh) * 64 + lh) * 8 + (c & 7)],
                           cv.s16, __ATOMIC_RELAXED, SCOPE_AGENT);
      }
    }
    ++target; gbar(arr, gflag, epoch, j, target);
  }
}

// ---------------- host ----------------
extern "C" void kernel_launch(void* const* d_in, const int* in_sizes, int n_in,
                              void* d_out, int out_size, void* d_ws, size_t ws_size,
                              hipStream_t stream) {
  const float* x       = (const float*)d_in[0];
  const float* W1      = (const float*)d_in[1];
  const float* b1      = (const float*)d_in[2];
  const float* ln_g    = (const float*)d_in[3];
  const float* ln_b    = (const float*)d_in[4];
  const float* W2      = (const float*)d_in[5];
  const float* b2      = (const float*)d_in[6];
  const float* init_hx = (const float*)d_in[7];
  float* out = (float*)d_out;

  char* ws = (char*)d_ws;
  __bf16* w1p    = (__bf16*)(ws);                        // 16 MB @ 0
  __bf16* w2p    = (__bf16*)(ws + 16777216ull);          // 8 MB
  __bf16* hbf    = (__bf16*)(ws + 25165824ull);          // 512 KB
  __bf16* hxbf   = (__bf16*)(ws + 25690112ull);          // 128 KB
  float* hxf32   = (float*)(ws + 25821184ull);           // 256 KB
  unsigned* arr  = (unsigned*)(ws + 26083328ull);        // 32 KB arrival flags
  unsigned* gflag= (unsigned*)(ws + 26116096ull);        // 1 KB group flags
  unsigned* epoch= (unsigned*)(ws + 26117120ull);        // epoch line
  __bf16* xbf    = (__bf16*)(ws + 28311552ull);          // 64 MB @ 27 MB
  const bool use_xbf = (ws_size >= 28311552ull + 67108864ull);

  prep_w1<<<4096, 256, 0, stream>>>(W1, w1p);
  prep_w2<<<2048, 256, 0, stream>>>(W2, w2p);
  prep_state<<<256, 256, 0, stream>>>(init_hx, hxf32, hxbf, arr);
  if (use_xbf) {
    prep_x<<<16384, 256, 0, stream>>>(x, xbf);
    rnn_persist<true><<<NBLK, NTHR, 0, stream>>>(
        x, b1, ln_g, ln_b, b2, out, w1p, w2p, xbf, hbf, hxbf, hxf32, arr, gflag, epoch);
  } else {
    rnn_persist<false><<<NBLK, NTHR, 0, stream>>>(
        x, b1, ln_g, ln_b, b2, out, w1p, w2p, xbf, hbf, hxbf, hxf32, arr, gflag, epoch);
  }
}